// Round 3
// baseline (1517.162 us; speedup 1.0000x reference)
//
#include <hip/hip_runtime.h>

#define NN 100000
#define NE 1600000
#define NBUK 1563          // ceil(NN/64) buckets of 64 nodes
#define EB 8192            // edges per scatter block

typedef __attribute__((ext_vector_type(8))) short v8s;
typedef __attribute__((ext_vector_type(4))) float v4f;

__device__ __forceinline__ unsigned short f2bf(float f) {
  unsigned int u = __float_as_uint(f);
  unsigned int r = (u + 0x7FFFu + ((u >> 16) & 1u)) >> 16;
  return (unsigned short)r;
}
__device__ __forceinline__ float bf2f(unsigned short w) {
  return __uint_as_float((unsigned int)w << 16);
}

// ---------------- bucket histogram ----------------

__global__ void k_zerob(int* __restrict__ hist) {
  int i = blockIdx.x * blockDim.x + threadIdx.x;
  if (i < NBUK) hist[i] = 0;
}

__global__ __launch_bounds__(256) void k_hist(const int* __restrict__ dst,
                                              int* __restrict__ hist) {
  __shared__ int lh[NBUK];
  int t = threadIdx.x;
  for (int i = t; i < NBUK; i += 256) lh[i] = 0;
  __syncthreads();
  int base = blockIdx.x * 16384;
  int lim = min(16384, NE - base);
  for (int j = t; j < lim; j += 256) atomicAdd(&lh[dst[base + j] >> 6], 1);
  __syncthreads();
  for (int i = t; i < NBUK; i += 256) {
    int c = lh[i];
    if (c) atomicAdd(&hist[i], c);
  }
}

// single-block chunked exclusive scan: hist -> bbase, gcur
__global__ __launch_bounds__(256) void k_scanb(const int* __restrict__ hist,
                                               int* __restrict__ bbase,
                                               int* __restrict__ gcur) {
  __shared__ int sc[256];
  __shared__ int carry;
  int t = threadIdx.x;
  if (t == 0) carry = 0;
  __syncthreads();
  for (int c = 0; c < (NBUK + 255) / 256; ++c) {
    int i = c * 256 + t;
    int vv = (i < NBUK) ? hist[i] : 0;
    sc[t] = vv;
    __syncthreads();
    for (int o = 1; o < 256; o <<= 1) {
      int uu = (t >= o) ? sc[t - o] : 0;
      __syncthreads();
      sc[t] += uu;
      __syncthreads();
    }
    int excl = carry + sc[t] - vv;
    if (i < NBUK) { bbase[i] = excl; gcur[i] = excl; }
    __syncthreads();
    if (t == 0) carry += sc[255];
    __syncthreads();
  }
}

// ---------------- LDS-staged bucket scatter ----------------
// staged[k] = (src<<6) | dstLocal, bucket-sorted; writes are linear runs.
extern __shared__ char smem_dyn[];
__global__ __launch_bounds__(256) void k_scatter(const int* __restrict__ src,
                                                 const int* __restrict__ dst,
                                                 int* __restrict__ gcur,
                                                 unsigned int* __restrict__ staged) {
  unsigned int* stageP = (unsigned int*)smem_dyn;              // EB
  unsigned short* stageB = (unsigned short*)(stageP + EB);     // EB
  int* lhist  = (int*)(stageB + EB);                           // NBUK
  int* lbase  = lhist + NBUK;
  int* lcur   = lbase + NBUK;
  int* gclaim = lcur + NBUK;
  __shared__ int sc[256];
  __shared__ int carry;
  int t = threadIdx.x;
  int e0 = blockIdx.x * EB;
  int ecnt = min(EB, NE - e0);
  for (int i = t; i < NBUK; i += 256) lhist[i] = 0;
  if (t == 0) carry = 0;
  __syncthreads();
  // pass A: local histogram
  for (int j = t; j < ecnt; j += 256) atomicAdd(&lhist[dst[e0 + j] >> 6], 1);
  __syncthreads();
  // local exclusive scan -> lbase, lcur
  for (int c = 0; c < (NBUK + 255) / 256; ++c) {
    int i = c * 256 + t;
    int vv = (i < NBUK) ? lhist[i] : 0;
    sc[t] = vv;
    __syncthreads();
    for (int o = 1; o < 256; o <<= 1) {
      int uu = (t >= o) ? sc[t - o] : 0;
      __syncthreads();
      sc[t] += uu;
      __syncthreads();
    }
    int excl = carry + sc[t] - vv;
    if (i < NBUK) { lbase[i] = excl; lcur[i] = excl; }
    __syncthreads();
    if (t == 0) carry += sc[255];
    __syncthreads();
  }
  // claim global ranges
  for (int b = t; b < NBUK; b += 256) {
    int c = lhist[b];
    gclaim[b] = c ? atomicAdd(&gcur[b], c) : 0;
  }
  __syncthreads();
  // pass B: place into LDS, bucket-sorted
  for (int j = t; j < ecnt; j += 256) {
    int s = src[e0 + j], d = dst[e0 + j];
    int b = d >> 6;
    int lp = atomicAdd(&lcur[b], 1);
    stageP[lp] = ((unsigned int)s << 6) | (unsigned int)(d & 63);
    stageB[lp] = (unsigned short)b;
  }
  __syncthreads();
  // linear write-out
  for (int i = t; i < ecnt; i += 256) {
    int b = stageB[i];
    staged[gclaim[b] + (i - lbase[b])] = stageP[i];
  }
}

// ---------------- weight pack ----------------

__global__ void k_packw(const float* __restrict__ W1l, const float* __restrict__ W1r,
                        unsigned short* __restrict__ Wcat) {
  int i = blockIdx.x * blockDim.x + threadIdx.x;  // 0..32767
  float f = (i < 16384) ? W1l[i] : W1r[i - 16384];
  Wcat[i] = f2bf(f);
}

// ---------------- MFMA GEMM: u = x@W1l^T, v = x@W1r^T (bf16 out) ----------
__global__ __launch_bounds__(256) void k_gemm1(
    const float* __restrict__ x, const unsigned short* __restrict__ Wcat,
    unsigned short* __restrict__ u, unsigned short* __restrict__ v) {
  int wave = threadIdx.x >> 6, l = threadIdx.x & 63;
  int m0 = blockIdx.x * 64 + wave * 16;
  if (m0 >= NN) return;
  int lr = l & 15, kq = l >> 4;
  int rowc = min(m0 + lr, NN - 1);

  v8s a[4];
#pragma unroll
  for (int ks = 0; ks < 4; ++ks) {
    const float* xp = x + (size_t)rowc * 128 + ks * 32 + kq * 8;
    float4 f0 = *(const float4*)xp;
    float4 f1 = *(const float4*)(xp + 4);
    v8s tv;
    tv[0] = (short)f2bf(f0.x); tv[1] = (short)f2bf(f0.y);
    tv[2] = (short)f2bf(f0.z); tv[3] = (short)f2bf(f0.w);
    tv[4] = (short)f2bf(f1.x); tv[5] = (short)f2bf(f1.y);
    tv[6] = (short)f2bf(f1.z); tv[7] = (short)f2bf(f1.w);
    a[ks] = tv;
  }

  v4f acc[16];
#pragma unroll
  for (int nt = 0; nt < 16; ++nt) acc[nt] = (v4f){0.f, 0.f, 0.f, 0.f};

#pragma unroll
  for (int nt = 0; nt < 16; ++nt) {
    const unsigned short* wrow = Wcat + (size_t)(nt * 16 + lr) * 128;
#pragma unroll
    for (int ks = 0; ks < 4; ++ks) {
      v8s b = *(const v8s*)(wrow + ks * 32 + kq * 8);
      acc[nt] = __builtin_amdgcn_mfma_f32_16x16x32_bf16(a[ks], b, acc[nt], 0, 0, 0);
    }
  }

#pragma unroll
  for (int nt = 0; nt < 16; ++nt) {
#pragma unroll
    for (int rr = 0; rr < 4; ++rr) {
      int mrow = m0 + kq * 4 + rr;
      if (mrow < NN) {
        unsigned short bv = f2bf(acc[nt][rr]);
        int col = nt * 16 + lr;
        if (nt < 8) u[(size_t)mrow * 128 + col] = bv;
        else        v[(size_t)mrow * 128 + (col - 128)] = bv;
      }
    }
  }
}

// ---------------- bucket layer-1: mean-agg(u) + v + b1 -> relu -> p,r ------
__global__ __launch_bounds__(256) void k_agg(
    const unsigned int* __restrict__ staged, const int* __restrict__ bbase,
    const int* __restrict__ hist,
    const unsigned short* __restrict__ u, const unsigned short* __restrict__ v,
    const float* __restrict__ b1,
    const float* __restrict__ W2l, const float* __restrict__ W2r,
    float* __restrict__ p, float* __restrict__ r) {
  __shared__ float acc[64][128];   // 32 KB
  __shared__ int degl[64];
  int bkt = blockIdx.x;
  int t = threadIdx.x, l = t & 63, w = t >> 6;
  for (int i = t; i < 64 * 128; i += 256) ((float*)acc)[i] = 0.f;
  if (t < 64) degl[t] = 0;
  __syncthreads();
  int st = bbase[bkt], cnt = hist[bkt];

  float b1l = b1[l], b1h = b1[64 + l];
  float w2a[8], w2b[8];
#pragma unroll
  for (int o = 0; o < 8; ++o) {
    const float* wr = (o < 4) ? (W2l + o * 128) : (W2r + (o - 4) * 128);
    w2a[o] = wr[l]; w2b[o] = wr[64 + l];
  }

  int e = w;
  for (; e + 12 < cnt; e += 16) {
    unsigned pk0 = staged[st + e];
    unsigned pk1 = staged[st + e + 4];
    unsigned pk2 = staged[st + e + 8];
    unsigned pk3 = staged[st + e + 12];
    const unsigned short* r0 = u + (size_t)(pk0 >> 6) * 128;
    const unsigned short* r1 = u + (size_t)(pk1 >> 6) * 128;
    const unsigned short* r2 = u + (size_t)(pk2 >> 6) * 128;
    const unsigned short* r3 = u + (size_t)(pk3 >> 6) * 128;
    float x0l = bf2f(r0[l]), x0h = bf2f(r0[64 + l]);
    float x1l = bf2f(r1[l]), x1h = bf2f(r1[64 + l]);
    float x2l = bf2f(r2[l]), x2h = bf2f(r2[64 + l]);
    float x3l = bf2f(r3[l]), x3h = bf2f(r3[64 + l]);
    int d0 = pk0 & 63, d1 = pk1 & 63, d2 = pk2 & 63, d3 = pk3 & 63;
    atomicAdd(&acc[d0][l], x0l);      atomicAdd(&acc[d0][64 + l], x0h);
    atomicAdd(&acc[d1][l], x1l);      atomicAdd(&acc[d1][64 + l], x1h);
    atomicAdd(&acc[d2][l], x2l);      atomicAdd(&acc[d2][64 + l], x2h);
    atomicAdd(&acc[d3][l], x3l);      atomicAdd(&acc[d3][64 + l], x3h);
    if (l == 0) {
      atomicAdd(&degl[d0], 1); atomicAdd(&degl[d1], 1);
      atomicAdd(&degl[d2], 1); atomicAdd(&degl[d3], 1);
    }
  }
  for (; e < cnt; e += 4) {
    unsigned pk = staged[st + e];
    const unsigned short* rr0 = u + (size_t)(pk >> 6) * 128;
    float xl = bf2f(rr0[l]), xh = bf2f(rr0[64 + l]);
    int dl = pk & 63;
    atomicAdd(&acc[dl][l], xl);
    atomicAdd(&acc[dl][64 + l], xh);
    if (l == 0) atomicAdd(&degl[dl], 1);
  }
  __syncthreads();

  int node0 = bkt * 64;
  for (int n = w * 16; n < w * 16 + 16; ++n) {
    int node = node0 + n;
    if (node >= NN) break;
    float inv = 1.f / (float)max(degl[n], 1);
    float vl = bf2f(v[(size_t)node * 128 + l]);
    float vh = bf2f(v[(size_t)node * 128 + 64 + l]);
    float hl = fmaxf(acc[n][l] * inv + vl + b1l, 0.f);
    float hh = fmaxf(acc[n][64 + l] * inv + vh + b1h, 0.f);
#pragma unroll
    for (int o = 0; o < 8; ++o) {
      float s = hl * w2a[o] + hh * w2b[o];
#pragma unroll
      for (int d2 = 32; d2; d2 >>= 1) s += __shfl_xor(s, d2, 64);
      if (l == o) {
        if (o < 4) p[(size_t)node * 4 + o] = s;
        else       r[(size_t)node * 4 + (o - 4)] = s;
      }
    }
  }
}

// ---------------- bucket layer-2: mean-agg(p) + b2 + r -> final linear -----
__global__ __launch_bounds__(256) void k_fin(
    const unsigned int* __restrict__ staged, const int* __restrict__ bbase,
    const int* __restrict__ hist,
    const float* __restrict__ p, const float* __restrict__ r,
    const float* __restrict__ b2,
    const float* __restrict__ Wlin, const float* __restrict__ blin,
    float* __restrict__ out) {
  __shared__ float acc2[64][4];
  __shared__ int degl[64];
  int bkt = blockIdx.x, t = threadIdx.x;
  if (t < 64) {
    degl[t] = 0;
    acc2[t][0] = 0.f; acc2[t][1] = 0.f; acc2[t][2] = 0.f; acc2[t][3] = 0.f;
  }
  __syncthreads();
  int st = bbase[bkt], cnt = hist[bkt];
  for (int j = t; j < cnt; j += 256) {
    unsigned pk = staged[st + j];
    int s = pk >> 6, dl = pk & 63;
    const float4 pv = *(const float4*)(p + (size_t)s * 4);
    atomicAdd(&acc2[dl][0], pv.x);
    atomicAdd(&acc2[dl][1], pv.y);
    atomicAdd(&acc2[dl][2], pv.z);
    atomicAdd(&acc2[dl][3], pv.w);
    atomicAdd(&degl[dl], 1);
  }
  __syncthreads();
  if (t < 64) {
    int node = bkt * 64 + t;
    if (node < NN) {
      float inv = 1.f / (float)max(degl[t], 1);
      const float4 rv = *(const float4*)(r + (size_t)node * 4);
      float g0 = acc2[t][0] * inv + b2[0] + rv.x;
      float g1 = acc2[t][1] * inv + b2[1] + rv.y;
      float g2 = acc2[t][2] * inv + b2[2] + rv.z;
      float g3 = acc2[t][3] * inv + b2[3] + rv.w;
      out[(size_t)node * 2 + 0] =
          g0 * Wlin[0] + g1 * Wlin[1] + g2 * Wlin[2] + g3 * Wlin[3] + blin[0];
      out[(size_t)node * 2 + 1] =
          g0 * Wlin[4] + g1 * Wlin[5] + g2 * Wlin[6] + g3 * Wlin[7] + blin[1];
    }
  }
}

// ---------------- launch ----------------

extern "C" void kernel_launch(void* const* d_in, const int* in_sizes, int n_in,
                              void* d_out, int out_size, void* d_ws, size_t ws_size,
                              hipStream_t stream) {
  const float* x    = (const float*)d_in[0];
  const int*   ei   = (const int*)d_in[1];
  const int*   src  = ei;
  const int*   dst  = ei + NE;
  const float* W1l  = (const float*)d_in[2];
  const float* b1   = (const float*)d_in[3];
  const float* W1r  = (const float*)d_in[4];
  const float* W2l  = (const float*)d_in[5];
  const float* b2   = (const float*)d_in[6];
  const float* W2r  = (const float*)d_in[7];
  const float* Wlin = (const float*)d_in[8];
  const float* blin = (const float*)d_in[9];
  float* out = (float*)d_out;

  char* w = (char*)d_ws;
  size_t o = 0;
  auto alloc = [&](size_t bytes) {
    void* pp = (void*)(w + o);
    o = (o + bytes + 255) & ~(size_t)255;
    return pp;
  };
  int* hist  = (int*)alloc(NBUK * 4);
  int* bbase = (int*)alloc(NBUK * 4);
  int* gcur  = (int*)alloc(NBUK * 4);
  unsigned int*  staged = (unsigned int*)alloc((size_t)NE * 4);
  unsigned short* Wcat  = (unsigned short*)alloc(256 * 128 * 2);
  unsigned short* ubuf  = (unsigned short*)alloc((size_t)NN * 128 * 2);
  unsigned short* vbuf  = (unsigned short*)alloc((size_t)NN * 128 * 2);
  float* pbuf = (float*)alloc((size_t)NN * 4 * 4);
  float* rbuf = (float*)alloc((size_t)NN * 4 * 4);

  const size_t scatter_lds = (size_t)EB * 4 + (size_t)EB * 2 + (size_t)4 * NBUK * 4;

  hipLaunchKernelGGL(k_zerob, dim3((NBUK + 255) / 256), dim3(256), 0, stream, hist);
  hipLaunchKernelGGL(k_hist,  dim3((NE + 16383) / 16384), dim3(256), 0, stream, dst, hist);
  hipLaunchKernelGGL(k_scanb, dim3(1), dim3(256), 0, stream, hist, bbase, gcur);
  hipLaunchKernelGGL(k_scatter, dim3((NE + EB - 1) / EB), dim3(256), scatter_lds, stream,
                     src, dst, gcur, staged);
  hipLaunchKernelGGL(k_packw, dim3(128), dim3(256), 0, stream, W1l, W1r, Wcat);
  hipLaunchKernelGGL(k_gemm1, dim3((NN + 63) / 64), dim3(256), 0, stream, x, Wcat, ubuf, vbuf);
  hipLaunchKernelGGL(k_agg,   dim3(NBUK), dim3(256), 0, stream,
                     staged, bbase, hist, ubuf, vbuf, b1, W2l, W2r, pbuf, rbuf);
  hipLaunchKernelGGL(k_fin,   dim3(NBUK), dim3(256), 0, stream,
                     staged, bbase, hist, pbuf, rbuf, b2, Wlin, blin, out);
}

// Round 4
// 362.966 us; speedup vs baseline: 4.1799x; 4.1799x over previous
//
#include <hip/hip_runtime.h>

#define NN 100000
#define NE 1600000
#define NBUK 1563          // ceil(NN/64) buckets of 64 nodes
#define EB 8192            // edges per scatter block

typedef __attribute__((ext_vector_type(8))) short v8s;
typedef __attribute__((ext_vector_type(4))) float v4f;

__device__ __forceinline__ unsigned short f2bf(float f) {
  unsigned int u = __float_as_uint(f);
  unsigned int r = (u + 0x7FFFu + ((u >> 16) & 1u)) >> 16;
  return (unsigned short)r;
}
__device__ __forceinline__ float bflo(unsigned int w) { return __uint_as_float(w << 16); }
__device__ __forceinline__ float bfhi(unsigned int w) { return __uint_as_float(w & 0xFFFF0000u); }
__device__ __forceinline__ float bf2f(unsigned short w) {
  return __uint_as_float((unsigned int)w << 16);
}

// ---------------- bucket histogram ----------------

__global__ void k_zerob(int* __restrict__ hist) {
  int i = blockIdx.x * blockDim.x + threadIdx.x;
  if (i < NBUK) hist[i] = 0;
}

__global__ __launch_bounds__(256) void k_hist(const int* __restrict__ dst,
                                              int* __restrict__ hist) {
  __shared__ int lh[NBUK];
  int t = threadIdx.x;
  for (int i = t; i < NBUK; i += 256) lh[i] = 0;
  __syncthreads();
  int base = blockIdx.x * 16384;
  int lim = min(16384, NE - base);
  for (int j = t; j < lim; j += 256) atomicAdd(&lh[dst[base + j] >> 6], 1);
  __syncthreads();
  for (int i = t; i < NBUK; i += 256) {
    int c = lh[i];
    if (c) atomicAdd(&hist[i], c);
  }
}

// single-block chunked exclusive scan: hist -> bbase, gcur
__global__ __launch_bounds__(256) void k_scanb(const int* __restrict__ hist,
                                               int* __restrict__ bbase,
                                               int* __restrict__ gcur) {
  __shared__ int sc[256];
  __shared__ int carry;
  int t = threadIdx.x;
  if (t == 0) carry = 0;
  __syncthreads();
  for (int c = 0; c < (NBUK + 255) / 256; ++c) {
    int i = c * 256 + t;
    int vv = (i < NBUK) ? hist[i] : 0;
    sc[t] = vv;
    __syncthreads();
    for (int o = 1; o < 256; o <<= 1) {
      int uu = (t >= o) ? sc[t - o] : 0;
      __syncthreads();
      sc[t] += uu;
      __syncthreads();
    }
    int excl = carry + sc[t] - vv;
    if (i < NBUK) { bbase[i] = excl; gcur[i] = excl; }
    __syncthreads();
    if (t == 0) carry += sc[255];
    __syncthreads();
  }
}

// ---------------- LDS-staged bucket scatter (linear global writes) ---------
// staged[k] = (src<<6) | dstLocal, bucket-sorted.
extern __shared__ char smem_dyn[];
__global__ __launch_bounds__(256) void k_scatter(const int* __restrict__ src,
                                                 const int* __restrict__ dst,
                                                 int* __restrict__ gcur,
                                                 unsigned int* __restrict__ staged) {
  unsigned int* stageP = (unsigned int*)smem_dyn;              // EB
  unsigned short* stageB = (unsigned short*)(stageP + EB);     // EB
  int* lhist  = (int*)(stageB + EB);                           // NBUK
  int* lbase  = lhist + NBUK;
  int* lcur   = lbase + NBUK;
  int* gclaim = lcur + NBUK;
  __shared__ int sc[256];
  __shared__ int carry;
  int t = threadIdx.x;
  int e0 = blockIdx.x * EB;
  int ecnt = min(EB, NE - e0);
  for (int i = t; i < NBUK; i += 256) lhist[i] = 0;
  if (t == 0) carry = 0;
  __syncthreads();
  for (int j = t; j < ecnt; j += 256) atomicAdd(&lhist[dst[e0 + j] >> 6], 1);
  __syncthreads();
  for (int c = 0; c < (NBUK + 255) / 256; ++c) {
    int i = c * 256 + t;
    int vv = (i < NBUK) ? lhist[i] : 0;
    sc[t] = vv;
    __syncthreads();
    for (int o = 1; o < 256; o <<= 1) {
      int uu = (t >= o) ? sc[t - o] : 0;
      __syncthreads();
      sc[t] += uu;
      __syncthreads();
    }
    int excl = carry + sc[t] - vv;
    if (i < NBUK) { lbase[i] = excl; lcur[i] = excl; }
    __syncthreads();
    if (t == 0) carry += sc[255];
    __syncthreads();
  }
  for (int b = t; b < NBUK; b += 256) {
    int c = lhist[b];
    gclaim[b] = c ? atomicAdd(&gcur[b], c) : 0;
  }
  __syncthreads();
  for (int j = t; j < ecnt; j += 256) {
    int s = src[e0 + j], d = dst[e0 + j];
    int b = d >> 6;
    int lp = atomicAdd(&lcur[b], 1);
    stageP[lp] = ((unsigned int)s << 6) | (unsigned int)(d & 63);
    stageB[lp] = (unsigned short)b;
  }
  __syncthreads();
  for (int i = t; i < ecnt; i += 256) {
    int b = stageB[i];
    staged[gclaim[b] + (i - lbase[b])] = stageP[i];
  }
}

// ---------------- per-bucket radix pass 2: staged -> CSR + off + deg -------
// Writes land only within the bucket's contiguous window (no write amp).
__global__ __launch_bounds__(256) void k_sort2(const unsigned int* __restrict__ staged,
                                               const int* __restrict__ bbase,
                                               const int* __restrict__ hist,
                                               int* __restrict__ csr,
                                               int* __restrict__ off,
                                               int* __restrict__ deg) {
  __shared__ int h64[64], c64[64];
  int bkt = blockIdx.x, t = threadIdx.x;
  if (t < 64) h64[t] = 0;
  __syncthreads();
  int st = bbase[bkt], cnt = hist[bkt];
  for (int j = t; j < cnt; j += 256) atomicAdd(&h64[staged[st + j] & 63], 1);
  __syncthreads();
  if (t < 64) {
    int v = h64[t];
    int inc = v;
    for (int o = 1; o < 64; o <<= 1) {
      int uu = __shfl_up(inc, o, 64);
      if (t >= o) inc += uu;
    }
    int excl = inc - v;
    c64[t] = excl;
    int node = bkt * 64 + t;
    if (node < NN) { off[node] = st + excl; deg[node] = v; }
  }
  __syncthreads();
  for (int j = t; j < cnt; j += 256) {
    unsigned pk = staged[st + j];
    int lp = atomicAdd(&c64[pk & 63], 1);
    csr[st + lp] = (int)(pk >> 6);
  }
}

// ---------------- weight pack ----------------

__global__ void k_packw(const float* __restrict__ W1l, const float* __restrict__ W1r,
                        unsigned short* __restrict__ Wcat) {
  int i = blockIdx.x * blockDim.x + threadIdx.x;  // 0..32767
  float f = (i < 16384) ? W1l[i] : W1r[i - 16384];
  Wcat[i] = f2bf(f);
}

// ---------------- MFMA GEMM: u = x@W1l^T, v = x@W1r^T (bf16 out) ----------
__global__ __launch_bounds__(256) void k_gemm1(
    const float* __restrict__ x, const unsigned short* __restrict__ Wcat,
    unsigned short* __restrict__ u, unsigned short* __restrict__ v) {
  int wave = threadIdx.x >> 6, l = threadIdx.x & 63;
  int m0 = blockIdx.x * 64 + wave * 16;
  if (m0 >= NN) return;
  int lr = l & 15, kq = l >> 4;
  int rowc = min(m0 + lr, NN - 1);

  v8s a[4];
#pragma unroll
  for (int ks = 0; ks < 4; ++ks) {
    const float* xp = x + (size_t)rowc * 128 + ks * 32 + kq * 8;
    float4 f0 = *(const float4*)xp;
    float4 f1 = *(const float4*)(xp + 4);
    v8s tv;
    tv[0] = (short)f2bf(f0.x); tv[1] = (short)f2bf(f0.y);
    tv[2] = (short)f2bf(f0.z); tv[3] = (short)f2bf(f0.w);
    tv[4] = (short)f2bf(f1.x); tv[5] = (short)f2bf(f1.y);
    tv[6] = (short)f2bf(f1.z); tv[7] = (short)f2bf(f1.w);
    a[ks] = tv;
  }

  v4f acc[16];
#pragma unroll
  for (int nt = 0; nt < 16; ++nt) acc[nt] = (v4f){0.f, 0.f, 0.f, 0.f};

#pragma unroll
  for (int nt = 0; nt < 16; ++nt) {
    const unsigned short* wrow = Wcat + (size_t)(nt * 16 + lr) * 128;
#pragma unroll
    for (int ks = 0; ks < 4; ++ks) {
      v8s b = *(const v8s*)(wrow + ks * 32 + kq * 8);
      acc[nt] = __builtin_amdgcn_mfma_f32_16x16x32_bf16(a[ks], b, acc[nt], 0, 0, 0);
    }
  }

#pragma unroll
  for (int nt = 0; nt < 16; ++nt) {
#pragma unroll
    for (int rr = 0; rr < 4; ++rr) {
      int mrow = m0 + kq * 4 + rr;
      if (mrow < NN) {
        unsigned short bv = f2bf(acc[nt][rr]);
        int col = nt * 16 + lr;
        if (nt < 8) u[(size_t)mrow * 128 + col] = bv;
        else        v[(size_t)mrow * 128 + (col - 128)] = bv;
      }
    }
  }
}

// ---------------- fused: mean-agg(u) + v + b1 -> relu -> h1; p=h1@W2l^T,
//                  r=h1@W2r^T. One wave per node; lane covers dims l, 64+l.
__global__ __launch_bounds__(256) void k_agg(
    const unsigned short* __restrict__ u, const unsigned short* __restrict__ v,
    const int* __restrict__ csr, const int* __restrict__ off, const int* __restrict__ deg,
    const float* __restrict__ b1,
    const float* __restrict__ W2l, const float* __restrict__ W2r,
    float* __restrict__ p, float* __restrict__ r) {
  int wid = (blockIdx.x * blockDim.x + threadIdx.x) >> 6;  // node
  int l = threadIdx.x & 63;
  if (wid >= NN) return;
  int cnt = deg[wid], st = off[wid];
  const unsigned int* ub = (const unsigned int*)u;

  float a0 = 0.f, a1 = 0.f;
  int e = 0;
  for (; e + 4 <= cnt; e += 4) {
    int s0 = csr[st + e], s1 = csr[st + e + 1], s2 = csr[st + e + 2], s3 = csr[st + e + 3];
    unsigned int w0 = ub[(size_t)s0 * 64 + l];
    unsigned int w1 = ub[(size_t)s1 * 64 + l];
    unsigned int w2 = ub[(size_t)s2 * 64 + l];
    unsigned int w3 = ub[(size_t)s3 * 64 + l];
    a0 += bflo(w0) + bflo(w1) + bflo(w2) + bflo(w3);
    a1 += bfhi(w0) + bfhi(w1) + bfhi(w2) + bfhi(w3);
  }
  for (; e < cnt; ++e) {
    unsigned int w = ub[(size_t)csr[st + e] * 64 + l];
    a0 += bflo(w); a1 += bfhi(w);
  }
  float inv = 1.f / (float)max(cnt, 1);
  unsigned int vw = ((const unsigned int*)v)[(size_t)wid * 64 + l];
  float2 bb = *(const float2*)(b1 + 2 * l);
  float h0 = fmaxf(a0 * inv + bflo(vw) + bb.x, 0.f);
  float h1 = fmaxf(a1 * inv + bfhi(vw) + bb.y, 0.f);

#pragma unroll
  for (int o = 0; o < 8; ++o) {
    const float* wr = (o < 4) ? (W2l + o * 128) : (W2r + (o - 4) * 128);
    float2 wv = *(const float2*)(wr + 2 * l);
    float s = h0 * wv.x + h1 * wv.y;
#pragma unroll
    for (int d = 32; d > 0; d >>= 1) s += __shfl_xor(s, d, 64);
    if (l == o) {
      if (o < 4) p[(size_t)wid * 4 + o] = s;
      else       r[(size_t)wid * 4 + (o - 4)] = s;
    }
  }
}

// ---------------- layer-2 aggregation (4-wide) + final linear ----------------
__global__ void k_final(const float* __restrict__ p, const float* __restrict__ r,
                        const int* __restrict__ csr, const int* __restrict__ off,
                        const int* __restrict__ deg,
                        const float* __restrict__ b2,
                        const float* __restrict__ Wlin, const float* __restrict__ blin,
                        float* __restrict__ out) {
  int i = blockIdx.x * blockDim.x + threadIdx.x;
  if (i >= NN) return;
  int cnt = deg[i], st = off[i];
  float a0 = 0.f, a1 = 0.f, a2 = 0.f, a3 = 0.f;
  for (int e = 0; e < cnt; ++e) {
    int s = csr[st + e];
    const float4 pv = *(const float4*)(p + (size_t)s * 4);
    a0 += pv.x; a1 += pv.y; a2 += pv.z; a3 += pv.w;
  }
  float inv = 1.f / (float)max(cnt, 1);
  float4 rv = *(const float4*)(r + (size_t)i * 4);
  float g0 = a0 * inv + b2[0] + rv.x;
  float g1 = a1 * inv + b2[1] + rv.y;
  float g2 = a2 * inv + b2[2] + rv.z;
  float g3 = a3 * inv + b2[3] + rv.w;
  out[(size_t)i * 2 + 0] = g0 * Wlin[0] + g1 * Wlin[1] + g2 * Wlin[2] + g3 * Wlin[3] + blin[0];
  out[(size_t)i * 2 + 1] = g0 * Wlin[4] + g1 * Wlin[5] + g2 * Wlin[6] + g3 * Wlin[7] + blin[1];
}

// ---------------- launch ----------------

extern "C" void kernel_launch(void* const* d_in, const int* in_sizes, int n_in,
                              void* d_out, int out_size, void* d_ws, size_t ws_size,
                              hipStream_t stream) {
  const float* x    = (const float*)d_in[0];
  const int*   ei   = (const int*)d_in[1];
  const int*   src  = ei;
  const int*   dst  = ei + NE;
  const float* W1l  = (const float*)d_in[2];
  const float* b1   = (const float*)d_in[3];
  const float* W1r  = (const float*)d_in[4];
  const float* W2l  = (const float*)d_in[5];
  const float* b2   = (const float*)d_in[6];
  const float* W2r  = (const float*)d_in[7];
  const float* Wlin = (const float*)d_in[8];
  const float* blin = (const float*)d_in[9];
  float* out = (float*)d_out;

  char* w = (char*)d_ws;
  size_t o = 0;
  auto alloc = [&](size_t bytes) {
    void* pp = (void*)(w + o);
    o = (o + bytes + 255) & ~(size_t)255;
    return pp;
  };
  int* hist  = (int*)alloc(NBUK * 4);
  int* bbase = (int*)alloc(NBUK * 4);
  int* gcur  = (int*)alloc(NBUK * 4);
  unsigned int*  staged = (unsigned int*)alloc((size_t)NE * 4);
  int* csr   = (int*)alloc((size_t)NE * 4);
  int* offs  = (int*)alloc(NN * 4);
  int* deg   = (int*)alloc(NN * 4);
  unsigned short* Wcat  = (unsigned short*)alloc(256 * 128 * 2);
  unsigned short* ubuf  = (unsigned short*)alloc((size_t)NN * 128 * 2);
  unsigned short* vbuf  = (unsigned short*)alloc((size_t)NN * 128 * 2);
  float* pbuf = (float*)alloc((size_t)NN * 4 * 4);
  float* rbuf = (float*)alloc((size_t)NN * 4 * 4);

  const size_t scatter_lds = (size_t)EB * 4 + (size_t)EB * 2 + (size_t)4 * NBUK * 4;

  hipLaunchKernelGGL(k_zerob, dim3((NBUK + 255) / 256), dim3(256), 0, stream, hist);
  hipLaunchKernelGGL(k_hist,  dim3((NE + 16383) / 16384), dim3(256), 0, stream, dst, hist);
  hipLaunchKernelGGL(k_scanb, dim3(1), dim3(256), 0, stream, hist, bbase, gcur);
  hipLaunchKernelGGL(k_scatter, dim3((NE + EB - 1) / EB), dim3(256), scatter_lds, stream,
                     src, dst, gcur, staged);
  hipLaunchKernelGGL(k_sort2, dim3(NBUK), dim3(256), 0, stream,
                     staged, bbase, hist, csr, offs, deg);
  hipLaunchKernelGGL(k_packw, dim3(128), dim3(256), 0, stream, W1l, W1r, Wcat);
  hipLaunchKernelGGL(k_gemm1, dim3((NN + 63) / 64), dim3(256), 0, stream, x, Wcat, ubuf, vbuf);
  hipLaunchKernelGGL(k_agg,   dim3((NN * 64 + 255) / 256), dim3(256), 0, stream,
                     ubuf, vbuf, csr, offs, deg, b1, W2l, W2r, pbuf, rbuf);
  hipLaunchKernelGGL(k_final, dim3((NN + 255) / 256), dim3(256), 0, stream,
                     pbuf, rbuf, csr, offs, deg, b2, Wlin, blin, out);
}